// Round 2
// baseline (2343.943 us; speedup 1.0000x reference)
//
#include <hip/hip_runtime.h>

// ---------------------------------------------------------------------------
// GIN forward on MI355X. CSR-by-dst built once per call, aggregation is
// atomic-free (wave per dst node, lane = feature dim). BN affine fused into
// the consumers of each layer's output. NOTE: harness passes integer inputs
// as int32 (not the reference's int64).
// ---------------------------------------------------------------------------

__global__ void hist_k(const int* __restrict__ dst, int* __restrict__ cnt, int E) {
  int stride = gridDim.x * blockDim.x;
  for (int i = blockIdx.x * blockDim.x + threadIdx.x; i < E; i += stride)
    atomicAdd(&cnt[dst[i]], 1);
}

__global__ void scan_a_k(const int* __restrict__ deg, int* __restrict__ rowptr,
                         int* __restrict__ bsum, int n) {
  __shared__ int s[256];
  int i = blockIdx.x * 256 + threadIdx.x;
  int v = (i < n) ? deg[i] : 0;
  s[threadIdx.x] = v;
  __syncthreads();
  for (int off = 1; off < 256; off <<= 1) {
    int t = (threadIdx.x >= off) ? s[threadIdx.x - off] : 0;
    __syncthreads();
    s[threadIdx.x] += t;
    __syncthreads();
  }
  if (i < n) rowptr[i] = s[threadIdx.x] - v;   // exclusive within block
  if (threadIdx.x == 255) bsum[blockIdx.x] = s[255];
}

__global__ void scan_b_k(int* __restrict__ bsum, int nb) {
  __shared__ int s[512];
  int t = threadIdx.x;
  int v = (t < nb) ? bsum[t] : 0;
  s[t] = v;
  __syncthreads();
  for (int off = 1; off < 512; off <<= 1) {
    int u = (t >= off) ? s[t - off] : 0;
    __syncthreads();
    s[t] += u;
    __syncthreads();
  }
  if (t < nb) bsum[t] = s[t] - v;              // exclusive block offsets
}

__global__ void scan_c_k(int* __restrict__ rowptr, int* __restrict__ cur,
                         const int* __restrict__ bsum, int n, int E) {
  int i = blockIdx.x * 256 + threadIdx.x;
  if (i < n) {
    int r = rowptr[i] + bsum[blockIdx.x];
    rowptr[i] = r;
    cur[i] = r;                                 // scatter cursor copy
  }
  if (i == 0) rowptr[n] = E;
}

__global__ void scatter_k(const int* __restrict__ src, const int* __restrict__ dst,
                          int* __restrict__ cur, int* __restrict__ ssrc,
                          int* __restrict__ seid, int E) {
  int stride = gridDim.x * blockDim.x;
  for (int i = blockIdx.x * blockDim.x + threadIdx.x; i < E; i += stride) {
    int d = dst[i];
    int pos = atomicAdd(&cur[d], 1);
    ssrc[pos] = src[i];
    seid[pos] = i;
  }
}

// One wave per dst node. lane = feature dim (D=64). Computes
// z[v] = h(v) + sum_e relu(h(src_e) + edge_attr_e @ ew + eb)
// where h() is node_table lookup (layer 0) or relu(affine(prev z2)) (layers>0).
template<bool FIRST>
__global__ void agg_k(const float* __restrict__ hprev, const int* __restrict__ x,
                      const float* __restrict__ ntab,
                      const int* __restrict__ rowptr, const int* __restrict__ ssrc,
                      const int* __restrict__ seid, const float* __restrict__ ea,
                      const float* __restrict__ ew, const float* __restrict__ eb,
                      const float* __restrict__ scsh,
                      float* __restrict__ zout, int n, int layer) {
  int gid = blockIdx.x * blockDim.x + threadIdx.x;
  int wid = gid >> 6;
  if (wid >= n) return;
  int lane = threadIdx.x & 63;
  const float* ewl = ew + layer * 7 * 64;
  float ew0 = ewl[0 * 64 + lane], ew1 = ewl[1 * 64 + lane], ew2 = ewl[2 * 64 + lane],
        ew3 = ewl[3 * 64 + lane], ew4 = ewl[4 * 64 + lane], ew5 = ewl[5 * 64 + lane],
        ew6 = ewl[6 * 64 + lane];
  float ebv = eb[layer * 64 + lane];
  float sc = 1.f, sh = 0.f;
  if (!FIRST) { sc = scsh[lane]; sh = scsh[64 + lane]; }

  auto H = [&](int row) -> float {
    if (FIRST) {
      return ntab[x[row] * 64 + lane];
    } else {
      float v = hprev[row * 64 + lane];
      return fmaxf(fmaf(v, sc, sh), 0.f);   // BN affine + relu of previous layer
    }
  };

  float acc = H(wid);                        // self term: z = h + agg
  int p0 = rowptr[wid], p1 = rowptr[wid + 1];
  for (int base = p0; base < p1; base += 64) {
    int m = p1 - base; if (m > 64) m = 64;
    int sv = 0, ev = 0;
    if (lane < m) { sv = ssrc[base + lane]; ev = seid[base + lane]; }
    for (int j = 0; j < m; j++) {
      int s = __shfl(sv, j);
      int e = __shfl(ev, j);
      float eav = (lane < 7) ? ea[e * 7 + lane] : 0.f;
      float hs = H(s);
      float emb = ebv;
      emb = fmaf(__shfl(eav, 0), ew0, emb);
      emb = fmaf(__shfl(eav, 1), ew1, emb);
      emb = fmaf(__shfl(eav, 2), ew2, emb);
      emb = fmaf(__shfl(eav, 3), ew3, emb);
      emb = fmaf(__shfl(eav, 4), ew4, emb);
      emb = fmaf(__shfl(eav, 5), ew5, emb);
      emb = fmaf(__shfl(eav, 6), ew6, emb);
      acc += fmaxf(hs + emb, 0.f);
    }
  }
  zout[wid * 64 + lane] = acc;
}

// z2 = relu(z @ w1 + b1) @ w2 + b2, plus per-dim sum / sumsq for BN stats.
__global__ void mlp_k(const float* __restrict__ zin, const float* __restrict__ w1,
                      const float* __restrict__ b1, const float* __restrict__ w2,
                      const float* __restrict__ b2, float* __restrict__ zout,
                      float* __restrict__ bnstats, int n, int layer) {
  __shared__ float w1s[64 * 64];
  __shared__ float w2s[64 * 64];
  __shared__ float red[128];
  for (int i = threadIdx.x; i < 64 * 64; i += blockDim.x) {
    w1s[i] = w1[layer * 64 * 64 + i];
    w2s[i] = w2[layer * 64 * 64 + i];
  }
  if (threadIdx.x < 128) red[threadIdx.x] = 0.f;
  int lane = threadIdx.x & 63;
  float b1v = b1[layer * 64 + lane], b2v = b2[layer * 64 + lane];
  __syncthreads();
  int wid = (blockIdx.x * blockDim.x + threadIdx.x) >> 6;
  int nw = (gridDim.x * blockDim.x) >> 6;
  float s1 = 0.f, s2 = 0.f;
  for (int r = wid; r < n; r += nw) {
    float z = zin[r * 64 + lane];
    float t = b1v;
#pragma unroll
    for (int i = 0; i < 64; i++)
      t = fmaf(__shfl(z, i), w1s[i * 64 + lane], t);
    t = fmaxf(t, 0.f);
    float o = b2v;
#pragma unroll
    for (int i = 0; i < 64; i++)
      o = fmaf(__shfl(t, i), w2s[i * 64 + lane], o);
    zout[r * 64 + lane] = o;
    s1 += o;
    s2 += o * o;
  }
  atomicAdd(&red[lane], s1);
  atomicAdd(&red[64 + lane], s2);
  __syncthreads();
  if (threadIdx.x < 128) atomicAdd(&bnstats[threadIdx.x], red[threadIdx.x]);
}

__global__ void fin_k(float* __restrict__ bnstats, const float* __restrict__ gamma,
                      const float* __restrict__ beta, float* __restrict__ scsh,
                      int n, int layer) {
  int d = threadIdx.x;
  float mu = bnstats[d] / (float)n;
  float var = bnstats[64 + d] / (float)n - mu * mu;
  float sc = gamma[layer * 64 + d] * rsqrtf(var + 1e-5f);
  scsh[d] = sc;
  scsh[64 + d] = beta[layer * 64 + d] - mu * sc;
  bnstats[d] = 0.f;        // reset for next layer's stats
  bnstats[64 + d] = 0.f;
}

// Segment-mean pool with layer-4 BN affine fused (no relu on last layer).
// batch[] is sorted, so each wave run-length-accumulates then flushes.
__global__ void pool_k(const float* __restrict__ z2, const float* __restrict__ scsh,
                       const int* __restrict__ batch, float* __restrict__ gsum,
                       float* __restrict__ gcnt, int n, int ch) {
  int wid = (blockIdx.x * blockDim.x + threadIdx.x) >> 6;
  int lane = threadIdx.x & 63;
  int v0 = wid * ch;
  if (v0 >= n) return;
  int v1 = v0 + ch; if (v1 > n) v1 = n;
  float sc = scsh[lane], sh = scsh[64 + lane];
  int curb = batch[v0];
  float acc = 0.f;
  int cnt = 0;
  for (int v = v0; v < v1; v++) {
    int b = batch[v];
    if (b != curb) {
      atomicAdd(&gsum[curb * 64 + lane], acc);
      if (lane == 0) atomicAdd(&gcnt[curb], (float)cnt);
      acc = 0.f; cnt = 0; curb = b;
    }
    acc += fmaf(z2[v * 64 + lane], sc, sh);
    cnt++;
  }
  atomicAdd(&gsum[curb * 64 + lane], acc);
  if (lane == 0) atomicAdd(&gcnt[curb], (float)cnt);
}

__global__ void head_k(const float* __restrict__ gsum, const float* __restrict__ gcnt,
                       const float* __restrict__ pw, const float* __restrict__ pb,
                       float* __restrict__ out, int B, int C) {
  for (int idx = threadIdx.x; idx < B * C; idx += blockDim.x) {
    int g = idx / C, c = idx % C;
    float inv = 1.f / fmaxf(gcnt[g], 1.f);
    float s = pb[c];
    for (int d = 0; d < 64; d++)
      s = fmaf(gsum[g * 64 + d] * inv, pw[d * C + c], s);
    out[idx] = s;
  }
}

extern "C" void kernel_launch(void* const* d_in, const int* in_sizes, int n_in,
                              void* d_out, int out_size, void* d_ws, size_t ws_size,
                              hipStream_t stream) {
  const int*   x     = (const int*)d_in[0];
  const int*   ei    = (const int*)d_in[1];
  const float* ea    = (const float*)d_in[2];
  const int*   batch = (const int*)d_in[3];
  const float* ntab  = (const float*)d_in[4];
  const float* ew    = (const float*)d_in[5];
  const float* eb    = (const float*)d_in[6];
  const float* w1    = (const float*)d_in[7];
  const float* b1    = (const float*)d_in[8];
  const float* w2    = (const float*)d_in[9];
  const float* b2    = (const float*)d_in[10];
  const float* gamma = (const float*)d_in[11];
  const float* beta  = (const float*)d_in[12];
  const float* pw    = (const float*)d_in[13];
  const float* pb    = (const float*)d_in[14];
  float* out = (float*)d_out;

  int N = in_sizes[0];
  int E = in_sizes[1] / 2;
  int L = in_sizes[6] / 64;   // eb is (L, 64)
  int C = in_sizes[14];
  int B = out_size / C;

  const int* src = ei;
  const int* dst = ei + E;

  // workspace carve (256B aligned)
  char* ws = (char*)d_ws;
  auto alloc = [&](size_t bytes) -> char* {
    char* p = ws;
    ws += (bytes + 255) & ~(size_t)255;
    return p;
  };
  float* zA      = (float*)alloc((size_t)N * 64 * 4);
  float* zB      = (float*)alloc((size_t)N * 64 * 4);
  int*   rowptr  = (int*)alloc((size_t)(N + 1) * 4);
  int*   cur     = (int*)alloc((size_t)N * 4);
  int*   ssrc    = (int*)alloc((size_t)E * 4);
  int*   seid    = (int*)alloc((size_t)E * 4);
  int*   bsum    = (int*)alloc(512 * 4);
  float* bnstats = (float*)alloc(128 * 4);
  float* scsh    = (float*)alloc(128 * 4);
  float* gsum    = (float*)alloc((size_t)B * 64 * 4);
  float* gcnt    = (float*)alloc((size_t)B * 4);

  hipMemsetAsync(cur, 0, (size_t)N * 4, stream);
  hipMemsetAsync(bnstats, 0, 128 * 4, stream);
  hipMemsetAsync(gsum, 0, (size_t)B * 64 * 4, stream);
  hipMemsetAsync(gcnt, 0, (size_t)B * 4, stream);

  // CSR build (reused across all layers)
  hist_k<<<1024, 256, 0, stream>>>(dst, cur, E);
  int NB = (N + 255) / 256;
  scan_a_k<<<NB, 256, 0, stream>>>(cur, rowptr, bsum, N);
  scan_b_k<<<1, 512, 0, stream>>>(bsum, NB);
  scan_c_k<<<NB, 256, 0, stream>>>(rowptr, cur, bsum, N, E);
  scatter_k<<<1024, 256, 0, stream>>>(src, dst, cur, ssrc, seid, E);

  int aggBlocks = (N * 64 + 255) / 256;
  int mlpBlocks = 2048;
  for (int l = 0; l < L; l++) {
    if (l == 0)
      agg_k<true><<<aggBlocks, 256, 0, stream>>>(zB, x, ntab, rowptr, ssrc, seid,
                                                 ea, ew, eb, scsh, zA, N, l);
    else
      agg_k<false><<<aggBlocks, 256, 0, stream>>>(zB, x, ntab, rowptr, ssrc, seid,
                                                  ea, ew, eb, scsh, zA, N, l);
    mlp_k<<<mlpBlocks, 256, 0, stream>>>(zA, w1, b1, w2, b2, zB, bnstats, N, l);
    fin_k<<<1, 64, 0, stream>>>(bnstats, gamma, beta, scsh, N, l);
  }

  int ch = 128;
  int poolWaves = (N + ch - 1) / ch;
  int poolBlocks = (poolWaves + 3) / 4;
  pool_k<<<poolBlocks, 256, 0, stream>>>(zB, scsh, batch, gsum, gcnt, N, ch);
  head_k<<<1, 256, 0, stream>>>(gsum, gcnt, pw, pb, out, B, C);
}

// Round 3
// 1266.630 us; speedup vs baseline: 1.8505x; 1.8505x over previous
//
#include <hip/hip_runtime.h>

// ---------------------------------------------------------------------------
// GIN forward on MI355X. CSR-by-dst built once per call, aggregation is
// atomic-free (wave per dst node, lane = feature dim). BN affine fused into
// the consumers of each layer's output. MLP: lane = row, weights via scalar
// (SGPR) loads, 64 independent accumulators -> pure-VALU FMA kernel.
// Integer inputs arrive as int32.
// ---------------------------------------------------------------------------

__global__ void hist_k(const int* __restrict__ dst, int* __restrict__ cnt, int E) {
  int stride = gridDim.x * blockDim.x;
  for (int i = blockIdx.x * blockDim.x + threadIdx.x; i < E; i += stride)
    atomicAdd(&cnt[dst[i]], 1);
}

__global__ void scan_a_k(const int* __restrict__ deg, int* __restrict__ rowptr,
                         int* __restrict__ bsum, int n) {
  __shared__ int s[256];
  int i = blockIdx.x * 256 + threadIdx.x;
  int v = (i < n) ? deg[i] : 0;
  s[threadIdx.x] = v;
  __syncthreads();
  for (int off = 1; off < 256; off <<= 1) {
    int t = (threadIdx.x >= off) ? s[threadIdx.x - off] : 0;
    __syncthreads();
    s[threadIdx.x] += t;
    __syncthreads();
  }
  if (i < n) rowptr[i] = s[threadIdx.x] - v;   // exclusive within block
  if (threadIdx.x == 255) bsum[blockIdx.x] = s[255];
}

__global__ void scan_b_k(int* __restrict__ bsum, int nb) {
  __shared__ int s[512];
  int t = threadIdx.x;
  int v = (t < nb) ? bsum[t] : 0;
  s[t] = v;
  __syncthreads();
  for (int off = 1; off < 512; off <<= 1) {
    int u = (t >= off) ? s[t - off] : 0;
    __syncthreads();
    s[t] += u;
    __syncthreads();
  }
  if (t < nb) bsum[t] = s[t] - v;              // exclusive block offsets
}

__global__ void scan_c_k(int* __restrict__ rowptr, int* __restrict__ cur,
                         const int* __restrict__ bsum, int n, int E) {
  int i = blockIdx.x * 256 + threadIdx.x;
  if (i < n) {
    int r = rowptr[i] + bsum[blockIdx.x];
    rowptr[i] = r;
    cur[i] = r;                                 // scatter cursor copy
  }
  if (i == 0) rowptr[n] = E;
}

__global__ void scatter_k(const int* __restrict__ src, const int* __restrict__ dst,
                          int* __restrict__ cur, int* __restrict__ ssrc,
                          int* __restrict__ seid, int E) {
  int stride = gridDim.x * blockDim.x;
  for (int i = blockIdx.x * blockDim.x + threadIdx.x; i < E; i += stride) {
    int d = dst[i];
    int pos = atomicAdd(&cur[d], 1);
    ssrc[pos] = src[i];
    seid[pos] = i;
  }
}

// One wave per dst node. lane = feature dim (D=64). Computes
// z[v] = h(v) + sum_e relu(h(src_e) + edge_attr_e @ ew + eb)
// where h() is node_table lookup (layer 0) or relu(affine(prev z2)) (layers>0).
template<bool FIRST>
__global__ void agg_k(const float* __restrict__ hprev, const int* __restrict__ x,
                      const float* __restrict__ ntab,
                      const int* __restrict__ rowptr, const int* __restrict__ ssrc,
                      const int* __restrict__ seid, const float* __restrict__ ea,
                      const float* __restrict__ ew, const float* __restrict__ eb,
                      const float* __restrict__ scsh,
                      float* __restrict__ zout, int n, int layer) {
  int gid = blockIdx.x * blockDim.x + threadIdx.x;
  int wid = gid >> 6;
  if (wid >= n) return;
  int lane = threadIdx.x & 63;
  const float* ewl = ew + layer * 7 * 64;
  float ew0 = ewl[0 * 64 + lane], ew1 = ewl[1 * 64 + lane], ew2 = ewl[2 * 64 + lane],
        ew3 = ewl[3 * 64 + lane], ew4 = ewl[4 * 64 + lane], ew5 = ewl[5 * 64 + lane],
        ew6 = ewl[6 * 64 + lane];
  float ebv = eb[layer * 64 + lane];
  float sc = 1.f, sh = 0.f;
  if (!FIRST) { sc = scsh[lane]; sh = scsh[64 + lane]; }

  auto H = [&](int row) -> float {
    if (FIRST) {
      return ntab[x[row] * 64 + lane];
    } else {
      float v = hprev[row * 64 + lane];
      return fmaxf(fmaf(v, sc, sh), 0.f);   // BN affine + relu of previous layer
    }
  };

  float acc = H(wid);                        // self term: z = h + agg
  int p0 = rowptr[wid], p1 = rowptr[wid + 1];
  for (int base = p0; base < p1; base += 64) {
    int m = p1 - base; if (m > 64) m = 64;
    int sv = 0, ev = 0;
    if (lane < m) { sv = ssrc[base + lane]; ev = seid[base + lane]; }
    for (int j = 0; j < m; j++) {
      int s = __shfl(sv, j);
      int e = __shfl(ev, j);
      float eav = (lane < 7) ? ea[e * 7 + lane] : 0.f;
      float hs = H(s);
      float emb = ebv;
      emb = fmaf(__shfl(eav, 0), ew0, emb);
      emb = fmaf(__shfl(eav, 1), ew1, emb);
      emb = fmaf(__shfl(eav, 2), ew2, emb);
      emb = fmaf(__shfl(eav, 3), ew3, emb);
      emb = fmaf(__shfl(eav, 4), ew4, emb);
      emb = fmaf(__shfl(eav, 5), ew5, emb);
      emb = fmaf(__shfl(eav, 6), ew6, emb);
      acc += fmaxf(hs + emb, 0.f);
    }
  }
  zout[wid * 64 + lane] = acc;
}

// MLP: z2 = relu(z @ w1 + b1) @ w2 + b2, per-dim sum/sumsq for BN stats.
// One wave per 64-row tile; lane = row; full row in VGPRs; weights are
// wave-uniform -> scalar loads, used as the SGPR operand of v_fma.
__global__ __launch_bounds__(64, 2)
void mlp_k(const float* __restrict__ zin, const float* __restrict__ w1g,
           const float* __restrict__ b1, const float* __restrict__ w2g,
           const float* __restrict__ b2, float* __restrict__ zout,
           float* __restrict__ bnstats, int n, int layer) {
  __shared__ float tile[64][65];
  int lane = threadIdx.x;
  int row = blockIdx.x * 64 + lane;
  bool valid = row < n;
  const float* wa = w1g + layer * 64 * 64;
  const float* wb = w2g + layer * 64 * 64;
  const float* b1l = b1 + layer * 64;
  const float* b2l = b2 + layer * 64;

  float z[64];
  if (valid) {
    const float4* zp = (const float4*)(zin + (size_t)row * 64);
#pragma unroll
    for (int k = 0; k < 16; k++) {
      float4 v = zp[k];
      z[4 * k + 0] = v.x; z[4 * k + 1] = v.y; z[4 * k + 2] = v.z; z[4 * k + 3] = v.w;
    }
  } else {
#pragma unroll
    for (int k = 0; k < 64; k++) z[k] = 0.f;
  }

  float t[64];
#pragma unroll
  for (int j = 0; j < 64; j++) t[j] = b1l[j];
#pragma unroll
  for (int i = 0; i < 64; i++) {
    float zi = z[i];
#pragma unroll
    for (int j = 0; j < 64; j++) t[j] = fmaf(zi, wa[i * 64 + j], t[j]);
  }
#pragma unroll
  for (int j = 0; j < 64; j++) t[j] = fmaxf(t[j], 0.f);

  float o[64];
#pragma unroll
  for (int j = 0; j < 64; j++) o[j] = b2l[j];
#pragma unroll
  for (int i = 0; i < 64; i++) {
    float ti = t[i];
#pragma unroll
    for (int j = 0; j < 64; j++) o[j] = fmaf(ti, wb[i * 64 + j], o[j]);
  }

  if (valid) {
    float4* op = (float4*)(zout + (size_t)row * 64);
#pragma unroll
    for (int k = 0; k < 16; k++) {
      float4 v;
      v.x = o[4 * k + 0]; v.y = o[4 * k + 1]; v.z = o[4 * k + 2]; v.w = o[4 * k + 3];
      op[k] = v;
    }
  }

  // BN stats: transpose through LDS (stride 65 -> conflict-free both ways).
#pragma unroll
  for (int j = 0; j < 64; j++) tile[lane][j] = valid ? o[j] : 0.f;
  __syncthreads();
  float s1 = 0.f, s2 = 0.f;
#pragma unroll
  for (int r = 0; r < 64; r++) {
    float v = tile[r][lane];
    s1 += v;
    s2 = fmaf(v, v, s2);
  }
  atomicAdd(&bnstats[lane], s1);
  atomicAdd(&bnstats[64 + lane], s2);
}

__global__ void fin_k(float* __restrict__ bnstats, const float* __restrict__ gamma,
                      const float* __restrict__ beta, float* __restrict__ scsh,
                      int n, int layer) {
  int d = threadIdx.x;
  float mu = bnstats[d] / (float)n;
  float var = bnstats[64 + d] / (float)n - mu * mu;
  float sc = gamma[layer * 64 + d] * rsqrtf(var + 1e-5f);
  scsh[d] = sc;
  scsh[64 + d] = beta[layer * 64 + d] - mu * sc;
  bnstats[d] = 0.f;        // reset for next layer's stats
  bnstats[64 + d] = 0.f;
}

// Segment-mean pool with layer-4 BN affine fused (no relu on last layer).
// batch[] is sorted, so each wave run-length-accumulates then flushes.
__global__ void pool_k(const float* __restrict__ z2, const float* __restrict__ scsh,
                       const int* __restrict__ batch, float* __restrict__ gsum,
                       float* __restrict__ gcnt, int n, int ch) {
  int wid = (blockIdx.x * blockDim.x + threadIdx.x) >> 6;
  int lane = threadIdx.x & 63;
  int v0 = wid * ch;
  if (v0 >= n) return;
  int v1 = v0 + ch; if (v1 > n) v1 = n;
  float sc = scsh[lane], sh = scsh[64 + lane];
  int curb = batch[v0];
  float acc = 0.f;
  int cnt = 0;
  for (int v = v0; v < v1; v++) {
    int b = batch[v];
    if (b != curb) {
      atomicAdd(&gsum[curb * 64 + lane], acc);
      if (lane == 0) atomicAdd(&gcnt[curb], (float)cnt);
      acc = 0.f; cnt = 0; curb = b;
    }
    acc += fmaf(z2[v * 64 + lane], sc, sh);
    cnt++;
  }
  atomicAdd(&gsum[curb * 64 + lane], acc);
  if (lane == 0) atomicAdd(&gcnt[curb], (float)cnt);
}

__global__ void head_k(const float* __restrict__ gsum, const float* __restrict__ gcnt,
                       const float* __restrict__ pw, const float* __restrict__ pb,
                       float* __restrict__ out, int B, int C) {
  for (int idx = threadIdx.x; idx < B * C; idx += blockDim.x) {
    int g = idx / C, c = idx % C;
    float inv = 1.f / fmaxf(gcnt[g], 1.f);
    float s = pb[c];
    for (int d = 0; d < 64; d++)
      s = fmaf(gsum[g * 64 + d] * inv, pw[d * C + c], s);
    out[idx] = s;
  }
}

extern "C" void kernel_launch(void* const* d_in, const int* in_sizes, int n_in,
                              void* d_out, int out_size, void* d_ws, size_t ws_size,
                              hipStream_t stream) {
  const int*   x     = (const int*)d_in[0];
  const int*   ei    = (const int*)d_in[1];
  const float* ea    = (const float*)d_in[2];
  const int*   batch = (const int*)d_in[3];
  const float* ntab  = (const float*)d_in[4];
  const float* ew    = (const float*)d_in[5];
  const float* eb    = (const float*)d_in[6];
  const float* w1    = (const float*)d_in[7];
  const float* b1    = (const float*)d_in[8];
  const float* w2    = (const float*)d_in[9];
  const float* b2    = (const float*)d_in[10];
  const float* gamma = (const float*)d_in[11];
  const float* beta  = (const float*)d_in[12];
  const float* pw    = (const float*)d_in[13];
  const float* pb    = (const float*)d_in[14];
  float* out = (float*)d_out;

  int N = in_sizes[0];
  int E = in_sizes[1] / 2;
  int L = in_sizes[6] / 64;   // eb is (L, 64)
  int C = in_sizes[14];
  int B = out_size / C;

  const int* src = ei;
  const int* dst = ei + E;

  // workspace carve (256B aligned)
  char* ws = (char*)d_ws;
  auto alloc = [&](size_t bytes) -> char* {
    char* p = ws;
    ws += (bytes + 255) & ~(size_t)255;
    return p;
  };
  float* zA      = (float*)alloc((size_t)N * 64 * 4);
  float* zB      = (float*)alloc((size_t)N * 64 * 4);
  int*   rowptr  = (int*)alloc((size_t)(N + 1) * 4);
  int*   cur     = (int*)alloc((size_t)N * 4);
  int*   ssrc    = (int*)alloc((size_t)E * 4);
  int*   seid    = (int*)alloc((size_t)E * 4);
  int*   bsum    = (int*)alloc(512 * 4);
  float* bnstats = (float*)alloc(128 * 4);
  float* scsh    = (float*)alloc(128 * 4);
  float* gsum    = (float*)alloc((size_t)B * 64 * 4);
  float* gcnt    = (float*)alloc((size_t)B * 4);

  hipMemsetAsync(cur, 0, (size_t)N * 4, stream);
  hipMemsetAsync(bnstats, 0, 128 * 4, stream);
  hipMemsetAsync(gsum, 0, (size_t)B * 64 * 4, stream);
  hipMemsetAsync(gcnt, 0, (size_t)B * 4, stream);

  // CSR build (reused across all layers)
  hist_k<<<1024, 256, 0, stream>>>(dst, cur, E);
  int NB = (N + 255) / 256;
  scan_a_k<<<NB, 256, 0, stream>>>(cur, rowptr, bsum, N);
  scan_b_k<<<1, 512, 0, stream>>>(bsum, NB);
  scan_c_k<<<NB, 256, 0, stream>>>(rowptr, cur, bsum, N, E);
  scatter_k<<<1024, 256, 0, stream>>>(src, dst, cur, ssrc, seid, E);

  int aggBlocks = (N * 64 + 255) / 256;
  int mlpBlocks = (N + 63) / 64;
  for (int l = 0; l < L; l++) {
    if (l == 0)
      agg_k<true><<<aggBlocks, 256, 0, stream>>>(zB, x, ntab, rowptr, ssrc, seid,
                                                 ea, ew, eb, scsh, zA, N, l);
    else
      agg_k<false><<<aggBlocks, 256, 0, stream>>>(zB, x, ntab, rowptr, ssrc, seid,
                                                  ea, ew, eb, scsh, zA, N, l);
    mlp_k<<<mlpBlocks, 64, 0, stream>>>(zA, w1, b1, w2, b2, zB, bnstats, N, l);
    fin_k<<<1, 64, 0, stream>>>(bnstats, gamma, beta, scsh, N, l);
  }

  int ch = 128;
  int poolWaves = (N + ch - 1) / ch;
  int poolBlocks = (poolWaves + 3) / 4;
  pool_k<<<poolBlocks, 256, 0, stream>>>(zB, scsh, batch, gsum, gcnt, N, ch);
  head_k<<<1, 256, 0, stream>>>(gsum, gcnt, pw, pb, out, B, C);
}

// Round 4
// 1204.647 us; speedup vs baseline: 1.9458x; 1.0515x over previous
//
#include <hip/hip_runtime.h>

// ---------------------------------------------------------------------------
// GIN forward on MI355X. CSR-by-dst built once per call; aggregation is
// atomic-free (wave per dst node, lane = feature dim, edge meta via scalar
// loads). MLP: lane = output dim, weight columns register-resident, rows
// streamed through per-wave LDS with broadcast reads; BN stats fall out
// per-lane. BN affine + relu fused into consumers. Integer inputs = int32.
// ---------------------------------------------------------------------------

__global__ void hist_k(const int* __restrict__ dst, int* __restrict__ cnt, int E) {
  int stride = gridDim.x * blockDim.x;
  for (int i = blockIdx.x * blockDim.x + threadIdx.x; i < E; i += stride)
    atomicAdd(&cnt[dst[i]], 1);
}

__global__ void scan_a_k(const int* __restrict__ deg, int* __restrict__ rowptr,
                         int* __restrict__ bsum, int n) {
  __shared__ int s[256];
  int i = blockIdx.x * 256 + threadIdx.x;
  int v = (i < n) ? deg[i] : 0;
  s[threadIdx.x] = v;
  __syncthreads();
  for (int off = 1; off < 256; off <<= 1) {
    int t = (threadIdx.x >= off) ? s[threadIdx.x - off] : 0;
    __syncthreads();
    s[threadIdx.x] += t;
    __syncthreads();
  }
  if (i < n) rowptr[i] = s[threadIdx.x] - v;   // exclusive within block
  if (threadIdx.x == 255) bsum[blockIdx.x] = s[255];
}

__global__ void scan_b_k(int* __restrict__ bsum, int nb) {
  __shared__ int s[512];
  int t = threadIdx.x;
  int v = (t < nb) ? bsum[t] : 0;
  s[t] = v;
  __syncthreads();
  for (int off = 1; off < 512; off <<= 1) {
    int u = (t >= off) ? s[t - off] : 0;
    __syncthreads();
    s[t] += u;
    __syncthreads();
  }
  if (t < nb) bsum[t] = s[t] - v;              // exclusive block offsets
}

__global__ void scan_c_k(int* __restrict__ rowptr, int* __restrict__ cur,
                         const int* __restrict__ bsum, int n, int E) {
  int i = blockIdx.x * 256 + threadIdx.x;
  if (i < n) {
    int r = rowptr[i] + bsum[blockIdx.x];
    rowptr[i] = r;
    cur[i] = r;                                 // scatter cursor copy
  }
  if (i == 0) rowptr[n] = E;
}

__global__ void scatter_k(const int* __restrict__ src, const int* __restrict__ dst,
                          int* __restrict__ cur, int* __restrict__ ssrc,
                          int* __restrict__ seid, int E) {
  int stride = gridDim.x * blockDim.x;
  for (int i = blockIdx.x * blockDim.x + threadIdx.x; i < E; i += stride) {
    int d = dst[i];
    int pos = atomicAdd(&cur[d], 1);
    ssrc[pos] = src[i];
    seid[pos] = i;
  }
}

// One wave per dst node. lane = feature dim (D=64).
// z[v] = h(v) + sum_e relu(h(src_e) + edge_attr_e @ ew + eb)
// All edge metadata (src id, edge id, edge_attr row) is wave-uniform ->
// scalar loads; only the h-row gather and the 7 fma are vector work.
template<bool FIRST>
__global__ void agg_k(const float* __restrict__ hprev, const int* __restrict__ x,
                      const float* __restrict__ ntab,
                      const int* __restrict__ rowptr, const int* __restrict__ ssrc,
                      const int* __restrict__ seid, const float* __restrict__ ea,
                      const float* __restrict__ ew, const float* __restrict__ eb,
                      const float* __restrict__ scsh,
                      float* __restrict__ zout, int n, int layer) {
  int gid = blockIdx.x * blockDim.x + threadIdx.x;
  int wid = gid >> 6;
  if (wid >= n) return;
  int lane = threadIdx.x & 63;
  const float* ewl = ew + layer * 7 * 64;
  float ew_[7];
#pragma unroll
  for (int k = 0; k < 7; k++) ew_[k] = ewl[k * 64 + lane];
  float ebv = eb[layer * 64 + lane];
  float sc = 1.f, sh = 0.f;
  if (!FIRST) { sc = scsh[lane]; sh = scsh[64 + lane]; }

  auto H = [&](int row) -> float {
    if (FIRST) {
      return ntab[x[row] * 64 + lane];
    } else {
      float v = hprev[(size_t)row * 64 + lane];
      return fmaxf(fmaf(v, sc, sh), 0.f);   // BN affine + relu of previous layer
    }
  };

  float acc = H(wid);                        // self term: z = h + agg
  int p0 = rowptr[wid], p1 = rowptr[wid + 1];
  if (p1 > p0) {
    int last = p1 - 1;
    for (int p = p0; p < p1; p += 4) {
      int i1 = p + 1 <= last ? p + 1 : last;
      int i2 = p + 2 <= last ? p + 2 : last;
      int i3 = p + 3 <= last ? p + 3 : last;
      int s0 = __builtin_amdgcn_readfirstlane(ssrc[p]);
      int e0 = __builtin_amdgcn_readfirstlane(seid[p]);
      int s1 = __builtin_amdgcn_readfirstlane(ssrc[i1]);
      int e1 = __builtin_amdgcn_readfirstlane(seid[i1]);
      int s2 = __builtin_amdgcn_readfirstlane(ssrc[i2]);
      int e2 = __builtin_amdgcn_readfirstlane(seid[i2]);
      int s3 = __builtin_amdgcn_readfirstlane(ssrc[i3]);
      int e3 = __builtin_amdgcn_readfirstlane(seid[i3]);
      float h0 = H(s0), h1 = H(s1), h2 = H(s2), h3 = H(s3);
      const float* A0 = ea + (size_t)e0 * 7;
      const float* A1 = ea + (size_t)e1 * 7;
      const float* A2 = ea + (size_t)e2 * 7;
      const float* A3 = ea + (size_t)e3 * 7;
      float m0 = ebv, m1 = ebv, m2 = ebv, m3 = ebv;
#pragma unroll
      for (int k = 0; k < 7; k++) {
        m0 = fmaf(A0[k], ew_[k], m0);
        m1 = fmaf(A1[k], ew_[k], m1);
        m2 = fmaf(A2[k], ew_[k], m2);
        m3 = fmaf(A3[k], ew_[k], m3);
      }
      acc += fmaxf(h0 + m0, 0.f);
      acc += (p + 1 < p1) ? fmaxf(h1 + m1, 0.f) : 0.f;
      acc += (p + 2 < p1) ? fmaxf(h2 + m2, 0.f) : 0.f;
      acc += (p + 3 < p1) ? fmaxf(h3 + m3, 0.f) : 0.f;
    }
  }
  zout[(size_t)wid * 64 + lane] = acc;
}

// MLP: z2 = relu(z @ w1 + b1) @ w2 + b2, per-dim sum/sumsq for BN stats.
// lane = output dim j. Weight columns w1[:,j], w2[:,j] live in VGPRs.
// Waves grab 16-row chunks grid-stride; rows staged coalesced into a
// per-wave LDS region, broadcast-read back (no barrier needed same-wave).
// GEMM2 broadcasts the lane-distributed intermediate via readlane (shfl
// with compile-constant lane).
__global__ __launch_bounds__(256)
void mlp_k(const float* __restrict__ zin, const float* __restrict__ w1g,
           const float* __restrict__ b1, const float* __restrict__ w2g,
           const float* __restrict__ b2, float* __restrict__ zout,
           float* __restrict__ bnstats, int n, int layer) {
  __shared__ float zs[4][16 * 64];
  __shared__ float red[128];
  int lane = threadIdx.x & 63;
  int wv = threadIdx.x >> 6;
  if (threadIdx.x < 128) red[threadIdx.x] = 0.f;
  __syncthreads();

  const float* wa = w1g + layer * 4096;
  const float* wb = w2g + layer * 4096;
  float w1c[64], w2c[64];
#pragma unroll
  for (int i = 0; i < 64; i++) w1c[i] = wa[i * 64 + lane];
#pragma unroll
  for (int i = 0; i < 64; i++) w2c[i] = wb[i * 64 + lane];
  float b1v = b1[layer * 64 + lane], b2v = b2[layer * 64 + lane];

  float s1 = 0.f, s2 = 0.f;
  int wid = (blockIdx.x * blockDim.x + threadIdx.x) >> 6;
  int nw = (gridDim.x * blockDim.x) >> 6;
  int nchunks = (n + 15) / 16;
  for (int c = wid; c < nchunks; c += nw) {
    int r0 = c * 16;
    int nr = n - r0; if (nr > 16) nr = 16;
    // stage: nr*16 float4s, coalesced global load -> per-wave LDS region
    const float4* gz = (const float4*)(zin + (size_t)r0 * 64);
    float4* ls = (float4*)zs[wv];
    int nf4 = nr * 16;
#pragma unroll
    for (int k = 0; k < 4; k++) {
      int idx = k * 64 + lane;
      if (idx < nf4) ls[idx] = gz[idx];
    }
    for (int r = 0; r < nr; r++) {
      const float4* zr = (const float4*)&zs[wv][r * 64];
      float t0 = b1v, t1 = 0.f, t2 = 0.f, t3 = 0.f;
#pragma unroll
      for (int i = 0; i < 16; i++) {
        float4 zv = zr[i];                 // uniform address -> broadcast
        t0 = fmaf(zv.x, w1c[4 * i + 0], t0);
        t1 = fmaf(zv.y, w1c[4 * i + 1], t1);
        t2 = fmaf(zv.z, w1c[4 * i + 2], t2);
        t3 = fmaf(zv.w, w1c[4 * i + 3], t3);
      }
      float t = fmaxf((t0 + t1) + (t2 + t3), 0.f);
      float o0 = b2v, o1 = 0.f, o2 = 0.f, o3 = 0.f;
#pragma unroll
      for (int i = 0; i < 16; i++) {
        o0 = fmaf(__shfl(t, 4 * i + 0), w2c[4 * i + 0], o0);
        o1 = fmaf(__shfl(t, 4 * i + 1), w2c[4 * i + 1], o1);
        o2 = fmaf(__shfl(t, 4 * i + 2), w2c[4 * i + 2], o2);
        o3 = fmaf(__shfl(t, 4 * i + 3), w2c[4 * i + 3], o3);
      }
      float o = (o0 + o1) + (o2 + o3);
      zout[(size_t)(r0 + r) * 64 + lane] = o;
      s1 += o;
      s2 = fmaf(o, o, s2);
    }
  }
  atomicAdd(&red[lane], s1);
  atomicAdd(&red[64 + lane], s2);
  __syncthreads();
  if (threadIdx.x < 128) atomicAdd(&bnstats[threadIdx.x], red[threadIdx.x]);
}

__global__ void fin_k(float* __restrict__ bnstats, const float* __restrict__ gamma,
                      const float* __restrict__ beta, float* __restrict__ scsh,
                      int n, int layer) {
  int d = threadIdx.x;
  float mu = bnstats[d] / (float)n;
  float var = bnstats[64 + d] / (float)n - mu * mu;
  float sc = gamma[layer * 64 + d] * rsqrtf(var + 1e-5f);
  scsh[d] = sc;
  scsh[64 + d] = beta[layer * 64 + d] - mu * sc;
  bnstats[d] = 0.f;        // reset for next layer's stats
  bnstats[64 + d] = 0.f;
}

// Segment-mean pool with layer-4 BN affine fused (no relu on last layer).
__global__ void pool_k(const float* __restrict__ z2, const float* __restrict__ scsh,
                       const int* __restrict__ batch, float* __restrict__ gsum,
                       float* __restrict__ gcnt, int n, int ch) {
  int wid = (blockIdx.x * blockDim.x + threadIdx.x) >> 6;
  int lane = threadIdx.x & 63;
  int v0 = wid * ch;
  if (v0 >= n) return;
  int v1 = v0 + ch; if (v1 > n) v1 = n;
  float sc = scsh[lane], sh = scsh[64 + lane];
  int curb = batch[v0];
  float acc = 0.f;
  int cnt = 0;
  for (int v = v0; v < v1; v++) {
    int b = batch[v];
    if (b != curb) {
      atomicAdd(&gsum[curb * 64 + lane], acc);
      if (lane == 0) atomicAdd(&gcnt[curb], (float)cnt);
      acc = 0.f; cnt = 0; curb = b;
    }
    acc += fmaf(z2[(size_t)v * 64 + lane], sc, sh);
    cnt++;
  }
  atomicAdd(&gsum[curb * 64 + lane], acc);
  if (lane == 0) atomicAdd(&gcnt[curb], (float)cnt);
}

__global__ void head_k(const float* __restrict__ gsum, const float* __restrict__ gcnt,
                       const float* __restrict__ pw, const float* __restrict__ pb,
                       float* __restrict__ out, int B, int C) {
  for (int idx = threadIdx.x; idx < B * C; idx += blockDim.x) {
    int g = idx / C, c = idx % C;
    float inv = 1.f / fmaxf(gcnt[g], 1.f);
    float s = pb[c];
    for (int d = 0; d < 64; d++)
      s = fmaf(gsum[g * 64 + d] * inv, pw[d * C + c], s);
    out[idx] = s;
  }
}

extern "C" void kernel_launch(void* const* d_in, const int* in_sizes, int n_in,
                              void* d_out, int out_size, void* d_ws, size_t ws_size,
                              hipStream_t stream) {
  const int*   x     = (const int*)d_in[0];
  const int*   ei    = (const int*)d_in[1];
  const float* ea    = (const float*)d_in[2];
  const int*   batch = (const int*)d_in[3];
  const float* ntab  = (const float*)d_in[4];
  const float* ew    = (const float*)d_in[5];
  const float* eb    = (const float*)d_in[6];
  const float* w1    = (const float*)d_in[7];
  const float* b1    = (const float*)d_in[8];
  const float* w2    = (const float*)d_in[9];
  const float* b2    = (const float*)d_in[10];
  const float* gamma = (const float*)d_in[11];
  const float* beta  = (const float*)d_in[12];
  const float* pw    = (const float*)d_in[13];
  const float* pb    = (const float*)d_in[14];
  float* out = (float*)d_out;

  int N = in_sizes[0];
  int E = in_sizes[1] / 2;
  int L = in_sizes[6] / 64;   // eb is (L, 64)
  int C = in_sizes[14];
  int B = out_size / C;

  const int* src = ei;
  const int* dst = ei + E;

  // workspace carve (256B aligned)
  char* ws = (char*)d_ws;
  auto alloc = [&](size_t bytes) -> char* {
    char* p = ws;
    ws += (bytes + 255) & ~(size_t)255;
    return p;
  };
  float* zA      = (float*)alloc((size_t)N * 64 * 4);
  float* zB      = (float*)alloc((size_t)N * 64 * 4);
  int*   rowptr  = (int*)alloc((size_t)(N + 1) * 4);
  int*   cur     = (int*)alloc((size_t)N * 4);
  int*   ssrc    = (int*)alloc((size_t)E * 4);
  int*   seid    = (int*)alloc((size_t)E * 4);
  int*   bsum    = (int*)alloc(512 * 4);
  float* bnstats = (float*)alloc(128 * 4);
  float* scsh    = (float*)alloc(128 * 4);
  float* gsum    = (float*)alloc((size_t)B * 64 * 4);
  float* gcnt    = (float*)alloc((size_t)B * 4);

  hipMemsetAsync(cur, 0, (size_t)N * 4, stream);
  hipMemsetAsync(bnstats, 0, 128 * 4, stream);
  hipMemsetAsync(gsum, 0, (size_t)B * 64 * 4, stream);
  hipMemsetAsync(gcnt, 0, (size_t)B * 4, stream);

  // CSR build (reused across all layers)
  hist_k<<<1024, 256, 0, stream>>>(dst, cur, E);
  int NB = (N + 255) / 256;
  scan_a_k<<<NB, 256, 0, stream>>>(cur, rowptr, bsum, N);
  scan_b_k<<<1, 512, 0, stream>>>(bsum, NB);
  scan_c_k<<<NB, 256, 0, stream>>>(rowptr, cur, bsum, N, E);
  scatter_k<<<1024, 256, 0, stream>>>(src, dst, cur, ssrc, seid, E);

  int aggBlocks = (N * 64 + 255) / 256;
  int mlpBlocks = (N + 63) / 64;   // ~1563 blocks, 4 waves each, grid-stride
  for (int l = 0; l < L; l++) {
    if (l == 0)
      agg_k<true><<<aggBlocks, 256, 0, stream>>>(zB, x, ntab, rowptr, ssrc, seid,
                                                 ea, ew, eb, scsh, zA, N, l);
    else
      agg_k<false><<<aggBlocks, 256, 0, stream>>>(zB, x, ntab, rowptr, ssrc, seid,
                                                  ea, ew, eb, scsh, zA, N, l);
    mlp_k<<<mlpBlocks, 256, 0, stream>>>(zA, w1, b1, w2, b2, zB, bnstats, N, l);
    fin_k<<<1, 64, 0, stream>>>(bnstats, gamma, beta, scsh, N, l);
  }

  int ch = 128;
  int poolWaves = (N + ch - 1) / ch;
  int poolBlocks = (poolWaves + 3) / 4;
  pool_k<<<poolBlocks, 256, 0, stream>>>(zB, scsh, batch, gsum, gcnt, N, ch);
  head_k<<<1, 256, 0, stream>>>(gsum, gcnt, pw, pb, out, B, C);
}

// Round 5
// 716.633 us; speedup vs baseline: 3.2708x; 1.6810x over previous
//
#include <hip/hip_runtime.h>

// ---------------------------------------------------------------------------
// GIN forward on MI355X. CSR-by-dst built once per call; scatter pre-gathers
// edge_attr into CSR order (8-float rows: 7 attrs + src id) so aggregation
// reads edge data sequentially via scalar loads. Aggregation: wave per dst
// node, lane = feature dim, 8-deep gather unroll. MLP: canonical 128x64
// tiled GEMM, 8x4 register tile per thread, A/t transposed in padded LDS.
// BN affine + relu fused into consumers. Integer inputs = int32.
// ---------------------------------------------------------------------------

__global__ void hist_k(const int* __restrict__ dst, int* __restrict__ cnt, int E) {
  int stride = gridDim.x * blockDim.x;
  for (int i = blockIdx.x * blockDim.x + threadIdx.x; i < E; i += stride)
    atomicAdd(&cnt[dst[i]], 1);
}

__global__ void scan_a_k(const int* __restrict__ deg, int* __restrict__ rowptr,
                         int* __restrict__ bsum, int n) {
  __shared__ int s[256];
  int i = blockIdx.x * 256 + threadIdx.x;
  int v = (i < n) ? deg[i] : 0;
  s[threadIdx.x] = v;
  __syncthreads();
  for (int off = 1; off < 256; off <<= 1) {
    int t = (threadIdx.x >= off) ? s[threadIdx.x - off] : 0;
    __syncthreads();
    s[threadIdx.x] += t;
    __syncthreads();
  }
  if (i < n) rowptr[i] = s[threadIdx.x] - v;   // exclusive within block
  if (threadIdx.x == 255) bsum[blockIdx.x] = s[255];
}

__global__ void scan_b_k(int* __restrict__ bsum, int nb) {
  __shared__ int s[512];
  int t = threadIdx.x;
  int v = (t < nb) ? bsum[t] : 0;
  s[t] = v;
  __syncthreads();
  for (int off = 1; off < 512; off <<= 1) {
    int u = (t >= off) ? s[t - off] : 0;
    __syncthreads();
    s[t] += u;
    __syncthreads();
  }
  if (t < nb) bsum[t] = s[t] - v;              // exclusive block offsets
}

__global__ void scan_c_k(int* __restrict__ rowptr, int* __restrict__ cur,
                         const int* __restrict__ bsum, int n, int E) {
  int i = blockIdx.x * 256 + threadIdx.x;
  if (i < n) {
    int r = rowptr[i] + bsum[blockIdx.x];
    rowptr[i] = r;
    cur[i] = r;                                 // scatter cursor copy
  }
  if (i == 0) rowptr[n] = E;
}

// Scatter edges into CSR order, pre-gathering edge_attr. Each CSR slot is
// 8 floats: [0..6] = edge_attr row, [7] = src node id (as int bits).
__global__ void scatter_k(const int* __restrict__ src, const int* __restrict__ dst,
                          int* __restrict__ cur, float* __restrict__ sea,
                          const float* __restrict__ ea, int E) {
  int stride = gridDim.x * blockDim.x;
  for (int i = blockIdx.x * blockDim.x + threadIdx.x; i < E; i += stride) {
    int d = dst[i];
    int pos = atomicAdd(&cur[d], 1);
    float* o = sea + (size_t)pos * 8;
    const float* a = ea + (size_t)i * 7;
#pragma unroll
    for (int k = 0; k < 7; k++) o[k] = a[k];
    o[7] = __int_as_float(src[i]);
  }
}

// One wave per dst node. lane = feature dim (D=64).
// z[v] = h(v) + sum_e relu(h(src_e) + edge_attr_e @ ew + eb)
// rowptr forced scalar via readfirstlane -> edge rows come in via s_load;
// 8 gathers kept in flight.
template<bool FIRST>
__global__ void agg_k(const float* __restrict__ hprev, const int* __restrict__ x,
                      const float* __restrict__ ntab, const int* __restrict__ rowptr,
                      const float* __restrict__ sea, const float* __restrict__ ew,
                      const float* __restrict__ eb, const float* __restrict__ scsh,
                      float* __restrict__ zout, int n, int layer) {
  int wid = (blockIdx.x * blockDim.x + threadIdx.x) >> 6;
  if (wid >= n) return;
  int lane = threadIdx.x & 63;
  const float* ewl = ew + layer * 448;
  float ew_[7];
#pragma unroll
  for (int k = 0; k < 7; k++) ew_[k] = ewl[k * 64 + lane];
  float ebv = eb[layer * 64 + lane];
  float sc = 1.f, sh = 0.f;
  if (!FIRST) { sc = scsh[lane]; sh = scsh[64 + lane]; }

  auto H = [&](int row) -> float {
    if (FIRST) {
      return ntab[x[row] * 64 + lane];
    } else {
      float v = hprev[(size_t)row * 64 + lane];
      return fmaxf(fmaf(v, sc, sh), 0.f);   // BN affine + relu of previous layer
    }
  };

  float acc = H(wid);                        // self term: z = h + agg
  int p0 = __builtin_amdgcn_readfirstlane(rowptr[wid]);
  int p1 = __builtin_amdgcn_readfirstlane(rowptr[wid + 1]);
  for (int p = p0; p < p1; p += 8) {
    const float* R[8];
    int srcv[8];
#pragma unroll
    for (int u = 0; u < 8; u++) {
      int t = p + u;
      int q = t < p1 ? t : p1 - 1;            // clamp (scalar select)
      R[u] = sea + (size_t)q * 8;
      srcv[u] = __builtin_amdgcn_readfirstlane(__float_as_int(R[u][7]));
    }
    float h[8];
#pragma unroll
    for (int u = 0; u < 8; u++) h[u] = H(srcv[u]);
    float m[8];
#pragma unroll
    for (int u = 0; u < 8; u++) m[u] = ebv;
#pragma unroll
    for (int k = 0; k < 7; k++) {
#pragma unroll
      for (int u = 0; u < 8; u++) m[u] = fmaf(R[u][k], ew_[k], m[u]);
    }
#pragma unroll
    for (int u = 0; u < 8; u++) {
      float contrib = fmaxf(h[u] + m[u], 0.f);
      acc += (p + u < p1) ? contrib : 0.f;
    }
  }
  zout[(size_t)wid * 64 + lane] = acc;
}

// MLP: z2 = relu(z @ w1 + b1) @ w2 + b2, per-dim sum/sumsq for BN stats.
// Tiled GEMM: block = 256 threads (16 tx x 16 ty), 128 rows x 64 cols.
// Thread (ty,tx) owns rows ty*8..+8, cols tx*4..+4 (8x4 register tile).
// A staged transposed As[k][r] (pad 129); t written back transposed into
// the same LDS; weights staged per-GEMM into Ws.
__global__ __launch_bounds__(256, 3)
void mlp_k(const float* __restrict__ zin, const float* __restrict__ w1g,
           const float* __restrict__ b1, const float* __restrict__ w2g,
           const float* __restrict__ b2, float* __restrict__ zout,
           float* __restrict__ bnstats, int n, int layer) {
  __shared__ float As[64 * 129];
  __shared__ float Ws[64 * 64];
  __shared__ float red[128];
  int tid = threadIdx.x;
  int tx = tid & 15, ty = tid >> 4;
  if (tid < 128) red[tid] = 0.f;
  int r0 = blockIdx.x * 128;

  // stage A transposed + w1
  {
    const float4* gz = (const float4*)(zin + (size_t)r0 * 64);
#pragma unroll
    for (int it = 0; it < 8; it++) {
      int f4 = it * 256 + tid;                 // 0..2047 = 128 rows x 16 quads
      int row = f4 >> 4, kq = f4 & 15;
      float4 v = make_float4(0.f, 0.f, 0.f, 0.f);
      if (r0 + row < n) v = gz[f4];
      As[(4 * kq + 0) * 129 + row] = v.x;
      As[(4 * kq + 1) * 129 + row] = v.y;
      As[(4 * kq + 2) * 129 + row] = v.z;
      As[(4 * kq + 3) * 129 + row] = v.w;
    }
    const float* wa = w1g + layer * 4096;
#pragma unroll
    for (int it = 0; it < 16; it++) Ws[it * 256 + tid] = wa[it * 256 + tid];
  }
  __syncthreads();

  const float4 b1v = *(const float4*)(b1 + layer * 64 + tx * 4);
  float t[8][4];
#pragma unroll
  for (int rr = 0; rr < 8; rr++) {
    t[rr][0] = b1v.x; t[rr][1] = b1v.y; t[rr][2] = b1v.z; t[rr][3] = b1v.w;
  }
#pragma unroll 4
  for (int k = 0; k < 64; k++) {
    float a[8];
#pragma unroll
    for (int rr = 0; rr < 8; rr++) a[rr] = As[k * 129 + ty * 8 + rr];
    float4 b = *(const float4*)&Ws[k * 64 + tx * 4];
#pragma unroll
    for (int rr = 0; rr < 8; rr++) {
      t[rr][0] = fmaf(a[rr], b.x, t[rr][0]);
      t[rr][1] = fmaf(a[rr], b.y, t[rr][1]);
      t[rr][2] = fmaf(a[rr], b.z, t[rr][2]);
      t[rr][3] = fmaf(a[rr], b.w, t[rr][3]);
    }
  }
  __syncthreads();                             // As, Ws fully consumed

  // relu(t) transposed into As (As[k2][r]); stage w2
#pragma unroll
  for (int cc = 0; cc < 4; cc++)
#pragma unroll
    for (int rr = 0; rr < 8; rr++)
      As[(tx * 4 + cc) * 129 + ty * 8 + rr] = fmaxf(t[rr][cc], 0.f);
  {
    const float* wb = w2g + layer * 4096;
#pragma unroll
    for (int it = 0; it < 16; it++) Ws[it * 256 + tid] = wb[it * 256 + tid];
  }
  __syncthreads();

  const float4 b2v = *(const float4*)(b2 + layer * 64 + tx * 4);
  float o[8][4];
#pragma unroll
  for (int rr = 0; rr < 8; rr++) {
    o[rr][0] = b2v.x; o[rr][1] = b2v.y; o[rr][2] = b2v.z; o[rr][3] = b2v.w;
  }
#pragma unroll 4
  for (int k = 0; k < 64; k++) {
    float a[8];
#pragma unroll
    for (int rr = 0; rr < 8; rr++) a[rr] = As[k * 129 + ty * 8 + rr];
    float4 b = *(const float4*)&Ws[k * 64 + tx * 4];
#pragma unroll
    for (int rr = 0; rr < 8; rr++) {
      o[rr][0] = fmaf(a[rr], b.x, o[rr][0]);
      o[rr][1] = fmaf(a[rr], b.y, o[rr][1]);
      o[rr][2] = fmaf(a[rr], b.z, o[rr][2]);
      o[rr][3] = fmaf(a[rr], b.w, o[rr][3]);
    }
  }

  // store + BN stat partials (valid rows only)
  float s1[4] = {0.f, 0.f, 0.f, 0.f}, s2[4] = {0.f, 0.f, 0.f, 0.f};
#pragma unroll
  for (int rr = 0; rr < 8; rr++) {
    int grow = r0 + ty * 8 + rr;
    if (grow < n) {
      float4 v = make_float4(o[rr][0], o[rr][1], o[rr][2], o[rr][3]);
      *(float4*)(zout + (size_t)grow * 64 + tx * 4) = v;
#pragma unroll
      for (int cc = 0; cc < 4; cc++) {
        s1[cc] += o[rr][cc];
        s2[cc] = fmaf(o[rr][cc], o[rr][cc], s2[cc]);
      }
    }
  }
#pragma unroll
  for (int cc = 0; cc < 4; cc++) {             // reduce over the 4 ty-groups in wave
    s1[cc] += __shfl_xor(s1[cc], 16); s1[cc] += __shfl_xor(s1[cc], 32);
    s2[cc] += __shfl_xor(s2[cc], 16); s2[cc] += __shfl_xor(s2[cc], 32);
  }
  if ((tid & 48) == 0) {                       // lane < 16 of each wave
#pragma unroll
    for (int cc = 0; cc < 4; cc++) {
      atomicAdd(&red[tx * 4 + cc], s1[cc]);
      atomicAdd(&red[64 + tx * 4 + cc], s2[cc]);
    }
  }
  __syncthreads();
  if (tid < 128) atomicAdd(&bnstats[tid], red[tid]);
}

__global__ void fin_k(float* __restrict__ bnstats, const float* __restrict__ gamma,
                      const float* __restrict__ beta, float* __restrict__ scsh,
                      int n, int layer) {
  int d = threadIdx.x;
  float mu = bnstats[d] / (float)n;
  float var = bnstats[64 + d] / (float)n - mu * mu;
  float sc = gamma[layer * 64 + d] * rsqrtf(var + 1e-5f);
  scsh[d] = sc;
  scsh[64 + d] = beta[layer * 64 + d] - mu * sc;
  bnstats[d] = 0.f;        // reset for next layer's stats
  bnstats[64 + d] = 0.f;
}

// Segment-mean pool with last-layer BN affine fused (no relu on last layer).
__global__ void pool_k(const float* __restrict__ z2, const float* __restrict__ scsh,
                       const int* __restrict__ batch, float* __restrict__ gsum,
                       float* __restrict__ gcnt, int n, int ch) {
  int wid = (blockIdx.x * blockDim.x + threadIdx.x) >> 6;
  int lane = threadIdx.x & 63;
  int v0 = wid * ch;
  if (v0 >= n) return;
  int v1 = v0 + ch; if (v1 > n) v1 = n;
  float sc = scsh[lane], sh = scsh[64 + lane];
  int curb = batch[v0];
  float acc = 0.f;
  int cnt = 0;
  for (int v = v0; v < v1; v++) {
    int b = batch[v];
    if (b != curb) {
      atomicAdd(&gsum[curb * 64 + lane], acc);
      if (lane == 0) atomicAdd(&gcnt[curb], (float)cnt);
      acc = 0.f; cnt = 0; curb = b;
    }
    acc += fmaf(z2[(size_t)v * 64 + lane], sc, sh);
    cnt++;
  }
  atomicAdd(&gsum[curb * 64 + lane], acc);
  if (lane == 0) atomicAdd(&gcnt[curb], (float)cnt);
}

__global__ void head_k(const float* __restrict__ gsum, const float* __restrict__ gcnt,
                       const float* __restrict__ pw, const float* __restrict__ pb,
                       float* __restrict__ out, int B, int C) {
  for (int idx = threadIdx.x; idx < B * C; idx += blockDim.x) {
    int g = idx / C, c = idx % C;
    float inv = 1.f / fmaxf(gcnt[g], 1.f);
    float s = pb[c];
    for (int d = 0; d < 64; d++)
      s = fmaf(gsum[g * 64 + d] * inv, pw[d * C + c], s);
    out[idx] = s;
  }
}

extern "C" void kernel_launch(void* const* d_in, const int* in_sizes, int n_in,
                              void* d_out, int out_size, void* d_ws, size_t ws_size,
                              hipStream_t stream) {
  const int*   x     = (const int*)d_in[0];
  const int*   ei    = (const int*)d_in[1];
  const float* ea    = (const float*)d_in[2];
  const int*   batch = (const int*)d_in[3];
  const float* ntab  = (const float*)d_in[4];
  const float* ew    = (const float*)d_in[5];
  const float* eb    = (const float*)d_in[6];
  const float* w1    = (const float*)d_in[7];
  const float* b1    = (const float*)d_in[8];
  const float* w2    = (const float*)d_in[9];
  const float* b2    = (const float*)d_in[10];
  const float* gamma = (const float*)d_in[11];
  const float* beta  = (const float*)d_in[12];
  const float* pw    = (const float*)d_in[13];
  const float* pb    = (const float*)d_in[14];
  float* out = (float*)d_out;

  int N = in_sizes[0];
  int E = in_sizes[1] / 2;
  int L = in_sizes[6] / 64;   // eb is (L, 64)
  int C = in_sizes[14];
  int B = out_size / C;

  const int* src = ei;
  const int* dst = ei + E;

  // workspace carve (256B aligned)
  char* ws = (char*)d_ws;
  auto alloc = [&](size_t bytes) -> char* {
    char* p = ws;
    ws += (bytes + 255) & ~(size_t)255;
    return p;
  };
  float* zA      = (float*)alloc((size_t)N * 64 * 4);
  float* zB      = (float*)alloc((size_t)N * 64 * 4);
  int*   rowptr  = (int*)alloc((size_t)(N + 1) * 4);
  int*   cur     = (int*)alloc((size_t)N * 4);
  float* sea     = (float*)alloc((size_t)E * 8 * 4);   // CSR edge rows: 7 attr + src
  int*   bsum    = (int*)alloc(512 * 4);
  float* bnstats = (float*)alloc(128 * 4);
  float* scsh    = (float*)alloc(128 * 4);
  float* gsum    = (float*)alloc((size_t)B * 64 * 4);
  float* gcnt    = (float*)alloc((size_t)B * 4);

  hipMemsetAsync(cur, 0, (size_t)N * 4, stream);
  hipMemsetAsync(bnstats, 0, 128 * 4, stream);
  hipMemsetAsync(gsum, 0, (size_t)B * 64 * 4, stream);
  hipMemsetAsync(gcnt, 0, (size_t)B * 4, stream);

  // CSR build (reused across all layers)
  hist_k<<<1024, 256, 0, stream>>>(dst, cur, E);
  int NB = (N + 255) / 256;
  scan_a_k<<<NB, 256, 0, stream>>>(cur, rowptr, bsum, N);
  scan_b_k<<<1, 512, 0, stream>>>(bsum, NB);
  scan_c_k<<<NB, 256, 0, stream>>>(rowptr, cur, bsum, N, E);
  scatter_k<<<1024, 256, 0, stream>>>(src, dst, cur, sea, ea, E);

  int aggBlocks = (N * 64 + 255) / 256;
  int mlpBlocks = (N + 127) / 128;
  for (int l = 0; l < L; l++) {
    if (l == 0)
      agg_k<true><<<aggBlocks, 256, 0, stream>>>(zB, x, ntab, rowptr, sea,
                                                 ew, eb, scsh, zA, N, l);
    else
      agg_k<false><<<aggBlocks, 256, 0, stream>>>(zB, x, ntab, rowptr, sea,
                                                  ew, eb, scsh, zA, N, l);
    mlp_k<<<mlpBlocks, 256, 0, stream>>>(zA, w1, b1, w2, b2, zB, bnstats, N, l);
    fin_k<<<1, 64, 0, stream>>>(bnstats, gamma, beta, scsh, N, l);
  }

  int ch = 128;
  int poolWaves = (N + ch - 1) / ch;
  int poolBlocks = (poolWaves + 3) / 4;
  pool_k<<<poolBlocks, 256, 0, stream>>>(zB, scsh, batch, gsum, gcnt, N, ch);
  head_k<<<1, 256, 0, stream>>>(gsum, gcnt, pw, pb, out, B, C);
}

// Round 6
// 654.069 us; speedup vs baseline: 3.5836x; 1.0957x over previous
//
#include <hip/hip_runtime.h>

// ---------------------------------------------------------------------------
// GIN forward on MI355X. CSR-by-dst built once per call; scatter pre-gathers
// edge_attr into CSR order (8-float rows: 7 attrs + src id). Aggregation:
// wave serves 8 consecutive nodes (prologue amortized), lane = feature dim,
// exact 4-wide edge unroll; layer 0 uses the constant node_table row (table
// has a single row). BN affine derived from raw per-layer stat slots by the
// consumers (no fin kernel). MLP: 128x64 tiled GEMM, 8x4 register tile,
// pad-132 transposed A => ds_read_b128 feeds. Integer inputs = int32.
// ---------------------------------------------------------------------------

__global__ void hist_k(const int* __restrict__ dst, int* __restrict__ cnt, int E) {
  int stride = gridDim.x * blockDim.x;
  for (int i = blockIdx.x * blockDim.x + threadIdx.x; i < E; i += stride)
    atomicAdd(&cnt[dst[i]], 1);
}

__global__ void scan_a_k(const int* __restrict__ deg, int* __restrict__ rowptr,
                         int* __restrict__ bsum, int n) {
  __shared__ int s[256];
  int i = blockIdx.x * 256 + threadIdx.x;
  int v = (i < n) ? deg[i] : 0;
  s[threadIdx.x] = v;
  __syncthreads();
  for (int off = 1; off < 256; off <<= 1) {
    int t = (threadIdx.x >= off) ? s[threadIdx.x - off] : 0;
    __syncthreads();
    s[threadIdx.x] += t;
    __syncthreads();
  }
  if (i < n) rowptr[i] = s[threadIdx.x] - v;   // exclusive within block
  if (threadIdx.x == 255) bsum[blockIdx.x] = s[255];
}

__global__ void scan_b_k(int* __restrict__ bsum, int nb) {
  __shared__ int s[512];
  int t = threadIdx.x;
  int v = (t < nb) ? bsum[t] : 0;
  s[t] = v;
  __syncthreads();
  for (int off = 1; off < 512; off <<= 1) {
    int u = (t >= off) ? s[t - off] : 0;
    __syncthreads();
    s[t] += u;
    __syncthreads();
  }
  if (t < nb) bsum[t] = s[t] - v;              // exclusive block offsets
}

__global__ void scan_c_k(int* __restrict__ rowptr, int* __restrict__ cur,
                         const int* __restrict__ bsum, int n, int E) {
  int i = blockIdx.x * 256 + threadIdx.x;
  if (i < n) {
    int r = rowptr[i] + bsum[blockIdx.x];
    rowptr[i] = r;
    cur[i] = r;                                 // scatter cursor copy
  }
  if (i == 0) rowptr[n] = E;
}

// Scatter edges into CSR order, pre-gathering edge_attr. Each CSR slot is
// 8 floats: [0..6] = edge_attr row, [7] = src node id (as int bits).
__global__ void scatter_k(const int* __restrict__ src, const int* __restrict__ dst,
                          int* __restrict__ cur, float* __restrict__ sea,
                          const float* __restrict__ ea, int E) {
  int stride = gridDim.x * blockDim.x;
  for (int i = blockIdx.x * blockDim.x + threadIdx.x; i < E; i += stride) {
    int d = dst[i];
    int pos = atomicAdd(&cur[d], 1);
    const float* a = ea + (size_t)i * 7;
    float4 lo = make_float4(a[0], a[1], a[2], a[3]);
    float4 hi = make_float4(a[4], a[5], a[6], __int_as_float(src[i]));
    float4* o = (float4*)(sea + (size_t)pos * 8);
    o[0] = lo;
    o[1] = hi;
  }
}

// MODE 0: first layer, single-row node table (h == const row, no gather).
// MODE 1: first layer, general table (fallback).
// MODE 2: later layers, h = relu(affine(prev)) gathered per edge.
// Each wave serves NPW consecutive nodes; lane = feature dim.
#define NPW 8
template<int MODE>
__global__ __launch_bounds__(256)
void agg_k(const float* __restrict__ hprev, const int* __restrict__ x,
           const float* __restrict__ ntab, const int* __restrict__ rowptr,
           const float* __restrict__ sea, const float* __restrict__ ewl,
           const float* __restrict__ ebl, const float* __restrict__ stats,
           const float* __restrict__ gam, const float* __restrict__ bet,
           float* __restrict__ zout, int n) {
  int wv = (blockIdx.x * blockDim.x + threadIdx.x) >> 6;
  int lane = threadIdx.x & 63;
  int g0 = wv * NPW;
  if (g0 >= n) return;
  int gend = g0 + NPW; if (gend > n) gend = n;

  float ew_[7];
#pragma unroll
  for (int k = 0; k < 7; k++) ew_[k] = ewl[k * 64 + lane];
  float ebv = ebl[lane];

  float cnst = 0.f, sc = 1.f, sh = 0.f;
  if (MODE == 0) cnst = ntab[lane];
  if (MODE == 2) {
    float s1 = stats[lane], s2 = stats[64 + lane];
    float mu = s1 / (float)n;
    float var = s2 / (float)n - mu * mu;
    sc = gam[lane] * rsqrtf(var + 1e-5f);
    sh = bet[lane] - mu * sc;
  }

  auto Hg = [&](int row) -> float {   // gathered h for MODE 1/2
    if (MODE == 1) {
      int xv = __builtin_amdgcn_readfirstlane(x[row]);
      return ntab[(size_t)xv * 64 + lane];
    } else {
      float v = hprev[(size_t)row * 64 + lane];
      return fmaxf(fmaf(v, sc, sh), 0.f);
    }
  };

  int pcur = __builtin_amdgcn_readfirstlane(rowptr[g0]);
  for (int nd = g0; nd < gend; nd++) {
    int pnext = __builtin_amdgcn_readfirstlane(rowptr[nd + 1]);
    float acc;
    if (MODE == 0) acc = cnst;
    else acc = Hg(nd);
    int p = pcur;
    for (; p + 4 <= pnext; p += 4) {
      const float* R0 = sea + (size_t)p * 8;
      const float* R1 = R0 + 8;
      const float* R2 = R0 + 16;
      const float* R3 = R0 + 24;
      float h0 = 0.f, h1 = 0.f, h2 = 0.f, h3 = 0.f;
      if (MODE != 0) {
        int s0 = __builtin_amdgcn_readfirstlane(__float_as_int(R0[7]));
        int s1 = __builtin_amdgcn_readfirstlane(__float_as_int(R1[7]));
        int s2 = __builtin_amdgcn_readfirstlane(__float_as_int(R2[7]));
        int s3 = __builtin_amdgcn_readfirstlane(__float_as_int(R3[7]));
        h0 = Hg(s0); h1 = Hg(s1); h2 = Hg(s2); h3 = Hg(s3);
      } else {
        h0 = h1 = h2 = h3 = cnst;
      }
      float m0 = ebv, m1 = ebv, m2 = ebv, m3 = ebv;
#pragma unroll
      for (int k = 0; k < 7; k++) {
        m0 = fmaf(R0[k], ew_[k], m0);
        m1 = fmaf(R1[k], ew_[k], m1);
        m2 = fmaf(R2[k], ew_[k], m2);
        m3 = fmaf(R3[k], ew_[k], m3);
      }
      acc += fmaxf(h0 + m0, 0.f);
      acc += fmaxf(h1 + m1, 0.f);
      acc += fmaxf(h2 + m2, 0.f);
      acc += fmaxf(h3 + m3, 0.f);
    }
    for (; p < pnext; p++) {
      const float* R0 = sea + (size_t)p * 8;
      float h0 = cnst;
      if (MODE != 0) {
        int s0 = __builtin_amdgcn_readfirstlane(__float_as_int(R0[7]));
        h0 = Hg(s0);
      }
      float m0 = ebv;
#pragma unroll
      for (int k = 0; k < 7; k++) m0 = fmaf(R0[k], ew_[k], m0);
      acc += fmaxf(h0 + m0, 0.f);
    }
    zout[(size_t)nd * 64 + lane] = acc;
    pcur = pnext;
  }
}

// MLP: z2 = relu(z @ w1 + b1) @ w2 + b2, per-dim sum/sumsq into this
// layer's stat slot. Tiled GEMM: 256 threads (16x16), 128 rows x 64 cols,
// 8x4 register tile. A transposed in LDS with stride 132 (16B-aligned rows
// of 8 => two ds_read_b128 per k-step).
#define ASTR 132
__global__ __launch_bounds__(256, 3)
void mlp_k(const float* __restrict__ zin, const float* __restrict__ w1l,
           const float* __restrict__ b1l, const float* __restrict__ w2l,
           const float* __restrict__ b2l, float* __restrict__ zout,
           float* __restrict__ statslot, int n) {
  __shared__ float As[64 * ASTR];
  __shared__ float Ws[4096];
  __shared__ float red[128];
  int tid = threadIdx.x;
  int tx = tid & 15, ty = tid >> 4;
  if (tid < 128) red[tid] = 0.f;
  int r0 = blockIdx.x * 128;

  // stage A transposed + w1
  {
    const float4* gz = (const float4*)(zin + (size_t)r0 * 64);
#pragma unroll
    for (int it = 0; it < 8; it++) {
      int f4 = it * 256 + tid;                 // 128 rows x 16 quads
      int row = f4 >> 4, kq = f4 & 15;
      float4 v = make_float4(0.f, 0.f, 0.f, 0.f);
      if (r0 + row < n) v = gz[f4];
      As[(4 * kq + 0) * ASTR + row] = v.x;
      As[(4 * kq + 1) * ASTR + row] = v.y;
      As[(4 * kq + 2) * ASTR + row] = v.z;
      As[(4 * kq + 3) * ASTR + row] = v.w;
    }
    const float4* wa = (const float4*)w1l;
    float4* wd = (float4*)Ws;
#pragma unroll
    for (int it = 0; it < 4; it++) wd[it * 256 + tid] = wa[it * 256 + tid];
  }
  __syncthreads();

  const float4 b1v = *(const float4*)(b1l + tx * 4);
  float t[8][4];
#pragma unroll
  for (int rr = 0; rr < 8; rr++) {
    t[rr][0] = b1v.x; t[rr][1] = b1v.y; t[rr][2] = b1v.z; t[rr][3] = b1v.w;
  }
#pragma unroll 8
  for (int k = 0; k < 64; k++) {
    float4 aA = *(const float4*)&As[k * ASTR + ty * 8];
    float4 aB = *(const float4*)&As[k * ASTR + ty * 8 + 4];
    float4 b = *(const float4*)&Ws[k * 64 + tx * 4];
    float a[8] = {aA.x, aA.y, aA.z, aA.w, aB.x, aB.y, aB.z, aB.w};
#pragma unroll
    for (int rr = 0; rr < 8; rr++) {
      t[rr][0] = fmaf(a[rr], b.x, t[rr][0]);
      t[rr][1] = fmaf(a[rr], b.y, t[rr][1]);
      t[rr][2] = fmaf(a[rr], b.z, t[rr][2]);
      t[rr][3] = fmaf(a[rr], b.w, t[rr][3]);
    }
  }
  __syncthreads();                             // As, Ws fully consumed

  // relu(t) transposed into As; stage w2
#pragma unroll
  for (int cc = 0; cc < 4; cc++)
#pragma unroll
    for (int rr = 0; rr < 8; rr++)
      As[(tx * 4 + cc) * ASTR + ty * 8 + rr] = fmaxf(t[rr][cc], 0.f);
  {
    const float4* wb = (const float4*)w2l;
    float4* wd = (float4*)Ws;
#pragma unroll
    for (int it = 0; it < 4; it++) wd[it * 256 + tid] = wb[it * 256 + tid];
  }
  __syncthreads();

  const float4 b2v = *(const float4*)(b2l + tx * 4);
  float o[8][4];
#pragma unroll
  for (int rr = 0; rr < 8; rr++) {
    o[rr][0] = b2v.x; o[rr][1] = b2v.y; o[rr][2] = b2v.z; o[rr][3] = b2v.w;
  }
#pragma unroll 8
  for (int k = 0; k < 64; k++) {
    float4 aA = *(const float4*)&As[k * ASTR + ty * 8];
    float4 aB = *(const float4*)&As[k * ASTR + ty * 8 + 4];
    float4 b = *(const float4*)&Ws[k * 64 + tx * 4];
    float a[8] = {aA.x, aA.y, aA.z, aA.w, aB.x, aB.y, aB.z, aB.w};
#pragma unroll
    for (int rr = 0; rr < 8; rr++) {
      o[rr][0] = fmaf(a[rr], b.x, o[rr][0]);
      o[rr][1] = fmaf(a[rr], b.y, o[rr][1]);
      o[rr][2] = fmaf(a[rr], b.z, o[rr][2]);
      o[rr][3] = fmaf(a[rr], b.w, o[rr][3]);
    }
  }

  // store + BN stat partials (valid rows only)
  float s1[4] = {0.f, 0.f, 0.f, 0.f}, s2[4] = {0.f, 0.f, 0.f, 0.f};
#pragma unroll
  for (int rr = 0; rr < 8; rr++) {
    int grow = r0 + ty * 8 + rr;
    if (grow < n) {
      float4 v = make_float4(o[rr][0], o[rr][1], o[rr][2], o[rr][3]);
      *(float4*)(zout + (size_t)grow * 64 + tx * 4) = v;
#pragma unroll
      for (int cc = 0; cc < 4; cc++) {
        s1[cc] += o[rr][cc];
        s2[cc] = fmaf(o[rr][cc], o[rr][cc], s2[cc]);
      }
    }
  }
#pragma unroll
  for (int cc = 0; cc < 4; cc++) {             // reduce over the 4 ty-groups in wave
    s1[cc] += __shfl_xor(s1[cc], 16); s1[cc] += __shfl_xor(s1[cc], 32);
    s2[cc] += __shfl_xor(s2[cc], 16); s2[cc] += __shfl_xor(s2[cc], 32);
  }
  if ((tid & 48) == 0) {                       // one ty-group per wave
#pragma unroll
    for (int cc = 0; cc < 4; cc++) {
      atomicAdd(&red[tx * 4 + cc], s1[cc]);
      atomicAdd(&red[64 + tx * 4 + cc], s2[cc]);
    }
  }
  __syncthreads();
  if (tid < 128) atomicAdd(&statslot[tid], red[tid]);
}

// Segment-mean pool with last-layer BN affine fused (no relu on last layer).
__global__ void pool_k(const float* __restrict__ z2, const float* __restrict__ stats,
                       const float* __restrict__ gam, const float* __restrict__ bet,
                       const int* __restrict__ batch, float* __restrict__ gsum,
                       float* __restrict__ gcnt, int n, int ch) {
  int wid = (blockIdx.x * blockDim.x + threadIdx.x) >> 6;
  int lane = threadIdx.x & 63;
  int v0 = wid * ch;
  if (v0 >= n) return;
  int v1 = v0 + ch; if (v1 > n) v1 = n;
  float st1 = stats[lane], st2 = stats[64 + lane];
  float mu = st1 / (float)n;
  float var = st2 / (float)n - mu * mu;
  float sc = gam[lane] * rsqrtf(var + 1e-5f);
  float sh = bet[lane] - mu * sc;
  int curb = batch[v0];
  float acc = 0.f;
  int cnt = 0;
  for (int v = v0; v < v1; v++) {
    int b = batch[v];
    if (b != curb) {
      atomicAdd(&gsum[curb * 64 + lane], acc);
      if (lane == 0) atomicAdd(&gcnt[curb], (float)cnt);
      acc = 0.f; cnt = 0; curb = b;
    }
    acc += fmaf(z2[(size_t)v * 64 + lane], sc, sh);
    cnt++;
  }
  atomicAdd(&gsum[curb * 64 + lane], acc);
  if (lane == 0) atomicAdd(&gcnt[curb], (float)cnt);
}

__global__ void head_k(const float* __restrict__ gsum, const float* __restrict__ gcnt,
                       const float* __restrict__ pw, const float* __restrict__ pb,
                       float* __restrict__ out, int B, int C) {
  for (int idx = threadIdx.x; idx < B * C; idx += blockDim.x) {
    int g = idx / C, c = idx % C;
    float inv = 1.f / fmaxf(gcnt[g], 1.f);
    float s = pb[c];
    for (int d = 0; d < 64; d++)
      s = fmaf(gsum[g * 64 + d] * inv, pw[d * C + c], s);
    out[idx] = s;
  }
}

extern "C" void kernel_launch(void* const* d_in, const int* in_sizes, int n_in,
                              void* d_out, int out_size, void* d_ws, size_t ws_size,
                              hipStream_t stream) {
  const int*   x     = (const int*)d_in[0];
  const int*   ei    = (const int*)d_in[1];
  const float* ea    = (const float*)d_in[2];
  const int*   batch = (const int*)d_in[3];
  const float* ntab  = (const float*)d_in[4];
  const float* ew    = (const float*)d_in[5];
  const float* eb    = (const float*)d_in[6];
  const float* w1    = (const float*)d_in[7];
  const float* b1    = (const float*)d_in[8];
  const float* w2    = (const float*)d_in[9];
  const float* b2    = (const float*)d_in[10];
  const float* gamma = (const float*)d_in[11];
  const float* beta  = (const float*)d_in[12];
  const float* pw    = (const float*)d_in[13];
  const float* pb    = (const float*)d_in[14];
  float* out = (float*)d_out;

  int N = in_sizes[0];
  int E = in_sizes[1] / 2;
  int L = in_sizes[6] / 64;        // eb is (L, 64)
  int C = in_sizes[14];
  int B = out_size / C;
  bool tab1 = (in_sizes[4] == 64); // node_table has a single row

  const int* src = ei;
  const int* dst = ei + E;

  // workspace carve (256B aligned)
  char* ws = (char*)d_ws;
  auto alloc = [&](size_t bytes) -> char* {
    char* p = ws;
    ws += (bytes + 255) & ~(size_t)255;
    return p;
  };
  float* zA      = (float*)alloc((size_t)N * 64 * 4);
  float* zB      = (float*)alloc((size_t)N * 64 * 4);
  int*   rowptr  = (int*)alloc((size_t)(N + 1) * 4);
  int*   cur     = (int*)alloc((size_t)N * 4);
  float* sea     = (float*)alloc((size_t)E * 8 * 4);   // CSR rows: 7 attr + src
  int*   bsum    = (int*)alloc(512 * 4);
  float* bnstats = (float*)alloc((size_t)L * 128 * 4); // per-layer stat slots
  float* gsum    = (float*)alloc((size_t)B * 64 * 4);
  float* gcnt    = (float*)alloc((size_t)B * 4);

  hipMemsetAsync(cur, 0, (size_t)N * 4, stream);
  hipMemsetAsync(bnstats, 0, (size_t)L * 128 * 4, stream);
  hipMemsetAsync(gsum, 0, (size_t)B * 64 * 4, stream);
  hipMemsetAsync(gcnt, 0, (size_t)B * 4, stream);

  // CSR build (reused across all layers)
  hist_k<<<2048, 256, 0, stream>>>(dst, cur, E);
  int NB = (N + 255) / 256;
  scan_a_k<<<NB, 256, 0, stream>>>(cur, rowptr, bsum, N);
  scan_b_k<<<1, 512, 0, stream>>>(bsum, NB);
  scan_c_k<<<NB, 256, 0, stream>>>(rowptr, cur, bsum, N, E);
  scatter_k<<<4096, 256, 0, stream>>>(src, dst, cur, sea, ea, E);

  int aggWaves = (N + NPW - 1) / NPW;
  int aggBlocks = (aggWaves * 64 + 255) / 256;
  int mlpBlocks = (N + 127) / 128;
  for (int l = 0; l < L; l++) {
    const float* ewl = ew + (size_t)l * 448;
    const float* ebl = eb + (size_t)l * 64;
    const float* stP = bnstats + (size_t)(l > 0 ? l - 1 : 0) * 128;
    const float* gmP = gamma + (size_t)(l > 0 ? l - 1 : 0) * 64;
    const float* btP = beta + (size_t)(l > 0 ? l - 1 : 0) * 64;
    if (l == 0) {
      if (tab1)
        agg_k<0><<<aggBlocks, 256, 0, stream>>>(zB, x, ntab, rowptr, sea, ewl, ebl,
                                                stP, gmP, btP, zA, N);
      else
        agg_k<1><<<aggBlocks, 256, 0, stream>>>(zB, x, ntab, rowptr, sea, ewl, ebl,
                                                stP, gmP, btP, zA, N);
    } else {
      agg_k<2><<<aggBlocks, 256, 0, stream>>>(zB, x, ntab, rowptr, sea, ewl, ebl,
                                              stP, gmP, btP, zA, N);
    }
    mlp_k<<<mlpBlocks, 256, 0, stream>>>(zA, w1 + (size_t)l * 4096, b1 + (size_t)l * 64,
                                         w2 + (size_t)l * 4096, b2 + (size_t)l * 64,
                                         zB, bnstats + (size_t)l * 128, N);
  }

  int ch = 128;
  int poolWaves = (N + ch - 1) / ch;
  int poolBlocks = (poolWaves + 3) / 4;
  pool_k<<<poolBlocks, 256, 0, stream>>>(zB, bnstats + (size_t)(L - 1) * 128,
                                         gamma + (size_t)(L - 1) * 64,
                                         beta + (size_t)(L - 1) * 64,
                                         batch, gsum, gcnt, N, ch);
  head_k<<<1, 256, 0, stream>>>(gsum, gcnt, pw, pb, out, B, C);
}